// Round 9
// baseline (1657.633 us; speedup 1.0000x reference)
//
#include <hip/hip_runtime.h>
#include <math.h>

#define Bq 8
#define Lq 65536
#define Hq 32
#define Nq 8
#define DEPq 4
#define LCq 64
#define NCq (Lq/LCq)     // 1024 chunks per b
#define GRPq 32          // chunks per group in pass2
#define NGq  (NCq/GRPq)  // 32 groups

// ---------------- conditioning MLP + FiLM ----------------
__global__ void k_cond_film(const float* __restrict__ prm,
                            const float* __restrict__ W1, const float* __restrict__ b1,
                            const float* __restrict__ W2, const float* __restrict__ b2,
                            const float* __restrict__ W3, const float* __restrict__ b3,
                            const float* __restrict__ filmW, const float* __restrict__ filmB,
                            float* __restrict__ film /* [DEP][B][2H] */)
{
    __shared__ float cond[Bq][32];
    int tid = threadIdx.x, d = blockIdx.x;
    if (tid < Bq) {
        float p0 = prm[tid*2+0], p1 = prm[tid*2+1];
        float c1[16];
        #pragma unroll
        for (int i=0;i<16;i++){ float v = W1[i*2+0]*p0 + W1[i*2+1]*p1 + b1[i]; c1[i]=v>0.f?v:0.f; }
        float c2[32];
        #pragma unroll
        for (int i=0;i<32;i++){ float a=b2[i];
            #pragma unroll
            for(int j=0;j<16;j++) a = fmaf(W2[i*16+j], c1[j], a);
            c2[i]=a>0.f?a:0.f; }
        #pragma unroll
        for (int i=0;i<32;i++){ float a=b3[i];
            #pragma unroll
            for(int j=0;j<32;j++) a = fmaf(W3[i*32+j], c2[j], a);
            cond[tid][i]=a>0.f?a:0.f; }
    }
    __syncthreads();
    int b = tid>>6, k = tid&63;
    float a = filmB[d*2*Hq + k];
    #pragma unroll
    for (int j=0;j<32;j++) a = fmaf(cond[b][j], filmW[(d*2*Hq + k)*32 + j], a);
    film[(d*Bq + b)*2*Hq + k] = a;
}

// ---------------- S4D derived params (f64 derivation, f32 tables) ----------------
__global__ void k_s4params(const float* __restrict__ log_dt, const float* __restrict__ logAre,
                           const float* __restrict__ Aim_, const float* __restrict__ Cre_,
                           const float* __restrict__ Cim_,
                           float* __restrict__ pw, float* __restrict__ pc2,
                           float* __restrict__ pwL, float* __restrict__ pwG)
{
    int idx = threadIdx.x; // DEP*H*N = 1024
    int d = idx/(Hq*Nq); int h = (idx/Nq)%Hq;
    double dt = exp((double)log_dt[d*Hq+h]);
    double Are = -exp((double)logAre[idx]);
    double Aim = (double)Aim_[idx];
    double dar = dt*Are, dai = dt*Aim;
    double er = exp(dar);
    double wr = er*cos(dai), wi = er*sin(dai);
    double em1r = wr - 1.0, em1i = wi;
    double den = Are*Are + Aim*Aim;
    double qr = (em1r*Are + em1i*Aim)/den;
    double qi = (em1i*Are - em1r*Aim)/den;
    double Cr = (double)Cre_[idx], Ci = (double)Cim_[idx];
    double eL = exp(dar*(double)LCq);
    double eG = exp(dar*(double)(LCq*GRPq));
    pw [idx*2+0]=(float)wr;  pw [idx*2+1]=(float)wi;
    pc2[idx*2+0]=(float)(2.0*(Cr*qr - Ci*qi)); pc2[idx*2+1]=(float)(2.0*(Cr*qi + Ci*qr));
    pwL[idx*2+0]=(float)(eL*cos(dai*(double)LCq));        pwL[idx*2+1]=(float)(eL*sin(dai*(double)LCq));
    pwG[idx*2+0]=(float)(eG*cos(dai*(double)(LCq*GRPq))); pwG[idx*2+1]=(float)(eG*sin(dai*(double)(LCq*GRPq)));
}

// ---------------- premix for depth 0: alpha = W0·eW, beta = W0·eb + b0 ----------------
__global__ void k_premix(const float* __restrict__ linW, const float* __restrict__ linB,
                         const float* __restrict__ eW, const float* __restrict__ eb,
                         float* __restrict__ ab0)
{
    int g = threadIdx.x;  // 32
    float a = 0.f, be = linB[g];
    #pragma unroll
    for (int h=0;h<Hq;h++){ a = fmaf(linW[g*Hq+h], eW[h], a); be = fmaf(linW[g*Hq+h], eb[h], be); }
    ab0[g] = a; ab0[32+g] = be;
}

// ---------------- k_first: u0 = relu(x*alpha+beta); chunk-local scan_0 -> sloc ----------------
__global__ __launch_bounds__(256, 4) void k_first(
    const float* __restrict__ x, const float* __restrict__ ab0,
    const float* __restrict__ pw, float* __restrict__ sloc)
{
    __shared__ float xs[LCq];
    int tid = threadIdx.x;
    int cg = blockIdx.x; int b = cg >> 10, c = cg & (NCq-1);
    if (tid < LCq) xs[tid] = x[(size_t)b*Lq + (size_t)c*LCq + tid];
    __syncthreads();
    int ch = tid >> 3, m = tid & 7;
    float wr = pw[(ch*Nq+m)*2], wi = pw[(ch*Nq+m)*2+1];
    float al = ab0[ch], be = ab0[32+ch];
    float sr = 0.f, si = 0.f;
    for (int j=0;j<LCq;j++){
        float u = fmaf(xs[j], al, be); u = u>0.f?u:0.f;
        float nr = fmaf(wr, sr, fmaf(-wi, si, u));
        float ni = fmaf(wr, si, wi*sr);
        sr=nr; si=ni;
    }
    size_t sb = ((size_t)(b*NCq + c)*Hq + ch)*16;
    sloc[sb+m] = sr; sloc[sb+8+m] = si;
}

// ---------------- pass2: two-level prefix over chunks, block per (b,h) ----------------
__global__ __launch_bounds__(256) void k_pass2(const float* __restrict__ sloc,
    const float* __restrict__ pwL, const float* __restrict__ pwG, float* __restrict__ sini)
{
    __shared__ float aux[NGq*Nq*2];
    int bid = blockIdx.x; int b = bid >> 5, h = bid & 31;
    int tid = threadIdx.x;
    int n = tid & 7, g2 = tid >> 3;   // g2 in [0,32)
    float wLr = pwL[(h*Nq+n)*2], wLi = pwL[(h*Nq+n)*2+1];
    float sr=0.f, si=0.f;
    for (int k=0;k<GRPq;k++){
        size_t off = ((size_t)(b*NCq + g2*GRPq+k)*Hq + h)*16;
        float lr = sloc[off+n], li = sloc[off+8+n];
        float nr = fmaf(wLr,sr, fmaf(-wLi,si, lr));
        float ni = fmaf(wLr,si, fmaf( wLi,sr, li));
        sr=nr; si=ni;
    }
    aux[(g2*8+n)*2+0]=sr; aux[(g2*8+n)*2+1]=si;
    __syncthreads();
    if (tid < 8) {
        float wGr = pwG[(h*Nq+tid)*2], wGi = pwG[(h*Nq+tid)*2+1];
        float pr=0.f, pi=0.f;
        for (int g=0; g<NGq; g++){
            float er_ = aux[(g*8+tid)*2+0], ei_ = aux[(g*8+tid)*2+1];
            aux[(g*8+tid)*2+0]=pr; aux[(g*8+tid)*2+1]=pi;
            float nr = fmaf(wGr,pr, fmaf(-wGi,pi, er_));
            float ni = fmaf(wGr,pi, fmaf( wGi,pr, ei_));
            pr=nr; pi=ni;
        }
    }
    __syncthreads();
    sr = aux[(g2*8+n)*2+0]; si = aux[(g2*8+n)*2+1];
    for (int k=0;k<GRPq;k++){
        size_t off = ((size_t)(b*NCq + g2*GRPq+k)*Hq + h)*16;
        float lr = sloc[off+n], li = sloc[off+8+n];
        sini[off+n] = sr; sini[off+8+n] = si;
        float nr = fmaf(wLr,sr, fmaf(-wLi,si, lr));
        float ni = fmaf(wLr,si, fmaf( wLi,sr, li));
        sr=nr; si=ni;
    }
}

// ---------------- k_main(d<3): phase-split chunk pipeline ----------------
// A: stage h_d -> htile  A1: mix_d -> utile  B: seeded scan_d + film -> utile
// C: residual -> htile + hbuf  C2: mix_{d+1} -> utile  D: local scan_{d+1} -> sloc
__global__ __launch_bounds__(256, 4) void k_main(
    const float* __restrict__ x, float* __restrict__ hbuf, int first,
    const float* __restrict__ eW, const float* __restrict__ eb,
    const float* __restrict__ ab0,
    const float* __restrict__ linW_d, const float* __restrict__ linB_d,
    const float* __restrict__ linW_n, const float* __restrict__ linB_n,
    const float* __restrict__ pw_d, const float* __restrict__ pc2_d,
    const float* __restrict__ pw_n,
    const float* __restrict__ sini, float* __restrict__ sloc,
    const float* __restrict__ Dskip, const float* __restrict__ film,
    const float* __restrict__ resw)
{
    __shared__ float htile[LCq][Hq];
    __shared__ float utile[LCq][Hq];
    __shared__ float xs[LCq];
    int tid = threadIdx.x;
    int cg = blockIdx.x; int b = cg >> 10, c = cg & (NCq-1);
    size_t recbase = ((size_t)b*Lq + (size_t)c*LCq)*Hq;   // float offset
    // ---- A: stage inputs
    if (first) {
        if (tid < LCq) xs[tid] = x[(size_t)b*Lq + (size_t)c*LCq + tid];
    } else {
        const float4* src = (const float4*)(hbuf + recbase);
        float4* dst = (float4*)(&htile[0][0]);
        dst[tid] = src[tid];
        dst[tid+256] = src[tid+256];
    }
    __syncthreads();
    int j = tid >> 2, q = tid & 3;
    int ch = tid >> 3, m = tid & 7;
    // ---- A1: mix_d -> utile
    if (first) {
        #pragma unroll
        for (int g8=0; g8<8; g8++){
            int g = q*8+g8;
            float u = fmaf(xs[j], ab0[g], ab0[32+g]);
            utile[j][g] = u>0.f?u:0.f;
        }
    } else {
        float hrow[Hq];
        #pragma unroll
        for (int k=0;k<8;k++) ((float4*)hrow)[k] = ((const float4*)(&htile[j][0]))[k];
        #pragma unroll
        for (int g8=0; g8<8; g8++){
            int g = q*8+g8;
            const float4* Wr = (const float4*)(linW_d + g*Hq);
            float a0=0.f,a1=0.f,a2=0.f,a3=0.f;
            #pragma unroll
            for (int k=0;k<8;k++){
                float4 w4 = Wr[k];
                a0 = fmaf(w4.x, hrow[4*k+0], a0);
                a1 = fmaf(w4.y, hrow[4*k+1], a1);
                a2 = fmaf(w4.z, hrow[4*k+2], a2);
                a3 = fmaf(w4.w, hrow[4*k+3], a3);
            }
            float u = linB_d[g] + ((a0+a1)+(a2+a3));
            utile[j][g] = u>0.f?u:0.f;
        }
    }
    __syncthreads();
    // ---- B: seeded scan_d + film -> y' in utile
    {
        float wr = pw_d[(ch*Nq+m)*2], wi = pw_d[(ch*Nq+m)*2+1];
        float cr = pc2_d[(ch*Nq+m)*2], ci = pc2_d[(ch*Nq+m)*2+1];
        size_t sb = ((size_t)(b*NCq + c)*Hq + ch)*16;
        float sr = sini[sb+m], si = sini[sb+8+m];
        float D  = Dskip[ch];
        float gf = film[b*2*Hq + ch], bf = film[b*2*Hq + Hq + ch];
        for (int jj=0;jj<LCq;jj++){
            float u = utile[jj][ch];
            float nr = fmaf(wr, sr, fmaf(-wi, si, u));
            float ni = fmaf(wr, si, wi*sr);
            sr=nr; si=ni;
            float y = fmaf(cr, nr, -(ci*ni));
            y += __shfl_xor(y, 1);
            y += __shfl_xor(y, 2);
            y += __shfl_xor(y, 4);
            if (m==0){
                float yt = fmaf(D, u, y);
                yt = fmaf(yt, gf, bf);
                utile[jj][ch] = yt>0.f?yt:0.f;
            }
        }
    }
    __syncthreads();
    // ---- C: residual -> htile + global hbuf
    {
        float hn[8];
        #pragma unroll
        for (int g8=0; g8<8; g8++){
            int g = q*8+g8;
            float yv = utile[j][g];
            float ho = first ? fmaf(xs[j], eW[g], eb[g]) : htile[j][g];
            hn[g8] = fmaf(resw[g], ho, yv);
        }
        float4 v0 = make_float4(hn[0],hn[1],hn[2],hn[3]);
        float4 v1 = make_float4(hn[4],hn[5],hn[6],hn[7]);
        float4* grec = (float4*)(hbuf + recbase) + (size_t)j*8 + q*2;
        grec[0] = v0; grec[1] = v1;
        ((float4*)&htile[j][0])[q*2+0] = v0;
        ((float4*)&htile[j][0])[q*2+1] = v1;
    }
    __syncthreads();
    // ---- C2: mix_{d+1} -> utile
    {
        float hrow[Hq];
        #pragma unroll
        for (int k=0;k<8;k++) ((float4*)hrow)[k] = ((const float4*)(&htile[j][0]))[k];
        #pragma unroll
        for (int g8=0; g8<8; g8++){
            int g = q*8+g8;
            const float4* Wr = (const float4*)(linW_n + g*Hq);
            float a0=0.f,a1=0.f,a2=0.f,a3=0.f;
            #pragma unroll
            for (int k=0;k<8;k++){
                float4 w4 = Wr[k];
                a0 = fmaf(w4.x, hrow[4*k+0], a0);
                a1 = fmaf(w4.y, hrow[4*k+1], a1);
                a2 = fmaf(w4.z, hrow[4*k+2], a2);
                a3 = fmaf(w4.w, hrow[4*k+3], a3);
            }
            float u = linB_n[g] + ((a0+a1)+(a2+a3));
            utile[j][g] = u>0.f?u:0.f;
        }
    }
    __syncthreads();
    // ---- D: local scan_{d+1} -> sloc
    {
        float vr = pw_n[(ch*Nq+m)*2], vi = pw_n[(ch*Nq+m)*2+1];
        float tr=0.f, ti=0.f;
        for (int jj=0;jj<LCq;jj++){
            float u = utile[jj][ch];
            float nr = fmaf(vr, tr, fmaf(-vi, ti, u));
            float ni = fmaf(vr, ti, vi*tr);
            tr=nr; ti=ni;
        }
        size_t sb = ((size_t)(b*NCq + c)*Hq + ch)*16;
        sloc[sb+m] = tr; sloc[sb+8+m] = ti;
    }
}

// ---------------- k_last (d=3): seeded scan + film + residual + contract + tanh ----------------
__global__ __launch_bounds__(256, 4) void k_last(
    const float* __restrict__ x, const float* __restrict__ hbuf,
    const float* __restrict__ linW_d, const float* __restrict__ linB_d,
    const float* __restrict__ pw_d, const float* __restrict__ pc2_d,
    const float* __restrict__ sini,
    const float* __restrict__ Dskip, const float* __restrict__ film,
    const float* __restrict__ resw, const float* __restrict__ cW,
    const float* __restrict__ cb, float* __restrict__ out)
{
    __shared__ float htile[LCq][Hq];
    __shared__ float utile[LCq][Hq];
    __shared__ float xs[LCq];
    int tid = threadIdx.x;
    int cg = blockIdx.x; int b = cg >> 10, c = cg & (NCq-1);
    size_t recbase = ((size_t)b*Lq + (size_t)c*LCq)*Hq;
    {
        const float4* src = (const float4*)(hbuf + recbase);
        float4* dst = (float4*)(&htile[0][0]);
        dst[tid] = src[tid];
        dst[tid+256] = src[tid+256];
        if (tid < LCq) xs[tid] = x[(size_t)b*Lq + (size_t)c*LCq + tid];
    }
    __syncthreads();
    int j = tid >> 2, q = tid & 3;
    int ch = tid >> 3, m = tid & 7;
    // mix_3 -> utile
    {
        float hrow[Hq];
        #pragma unroll
        for (int k=0;k<8;k++) ((float4*)hrow)[k] = ((const float4*)(&htile[j][0]))[k];
        #pragma unroll
        for (int g8=0; g8<8; g8++){
            int g = q*8+g8;
            const float4* Wr = (const float4*)(linW_d + g*Hq);
            float a0=0.f,a1=0.f,a2=0.f,a3=0.f;
            #pragma unroll
            for (int k=0;k<8;k++){
                float4 w4 = Wr[k];
                a0 = fmaf(w4.x, hrow[4*k+0], a0);
                a1 = fmaf(w4.y, hrow[4*k+1], a1);
                a2 = fmaf(w4.z, hrow[4*k+2], a2);
                a3 = fmaf(w4.w, hrow[4*k+3], a3);
            }
            float u = linB_d[g] + ((a0+a1)+(a2+a3));
            utile[j][g] = u>0.f?u:0.f;
        }
    }
    __syncthreads();
    // seeded scan_3 + film -> utile
    {
        float wr = pw_d[(ch*Nq+m)*2], wi = pw_d[(ch*Nq+m)*2+1];
        float cr = pc2_d[(ch*Nq+m)*2], ci = pc2_d[(ch*Nq+m)*2+1];
        size_t sb = ((size_t)(b*NCq + c)*Hq + ch)*16;
        float sr = sini[sb+m], si = sini[sb+8+m];
        float D  = Dskip[ch];
        float gf = film[b*2*Hq + ch], bf = film[b*2*Hq + Hq + ch];
        for (int jj=0;jj<LCq;jj++){
            float u = utile[jj][ch];
            float nr = fmaf(wr, sr, fmaf(-wi, si, u));
            float ni = fmaf(wr, si, wi*sr);
            sr=nr; si=ni;
            float y = fmaf(cr, nr, -(ci*ni));
            y += __shfl_xor(y, 1);
            y += __shfl_xor(y, 2);
            y += __shfl_xor(y, 4);
            if (m==0){
                float yt = fmaf(D, u, y);
                yt = fmaf(yt, gf, bf);
                utile[jj][ch] = yt>0.f?yt:0.f;
            }
        }
    }
    __syncthreads();
    // residual + contract + tanh + side-chain
    {
        float part = 0.f;
        #pragma unroll
        for (int g8=0; g8<8; g8++){
            int g = q*8+g8;
            float hn = fmaf(resw[g], htile[j][g], utile[j][g]);
            part = fmaf(cW[g], hn, part);
        }
        part += __shfl_xor(part, 1);
        part += __shfl_xor(part, 2);
        if (q == 0)
            out[(size_t)b*Lq + (size_t)c*LCq + j] = xs[j]*tanhf(part + cb[0]);
    }
}

// ---------------- diagnostic flag ----------------
__global__ void k_flag(float* __restrict__ out, int code) { out[0] = (float)code; }

extern "C" void kernel_launch(void* const* d_in, const int* in_sizes, int n_in,
                              void* d_out, int out_size, void* d_ws, size_t ws_size,
                              hipStream_t stream)
{
    const float* x    = (const float*)d_in[0];
    const float* prm  = (const float*)d_in[1];
    const float* W1   = (const float*)d_in[2];  const float* b1 = (const float*)d_in[3];
    const float* W2   = (const float*)d_in[4];  const float* b2 = (const float*)d_in[5];
    const float* W3   = (const float*)d_in[6];  const float* b3 = (const float*)d_in[7];
    const float* eW   = (const float*)d_in[8];  const float* eb = (const float*)d_in[9];
    const float* linW = (const float*)d_in[10]; const float* linB = (const float*)d_in[11];
    const float* log_dt = (const float*)d_in[12]; const float* logAre = (const float*)d_in[13];
    const float* Aim  = (const float*)d_in[14]; const float* Cre = (const float*)d_in[15];
    const float* Cim  = (const float*)d_in[16]; const float* Dskip = (const float*)d_in[17];
    const float* filmW= (const float*)d_in[18]; const float* filmB = (const float*)d_in[19];
    const float* resw = (const float*)d_in[20]; const float* cW = (const float*)d_in[21];
    const float* cb   = (const float*)d_in[22];

    float* sloc = (float*)d_ws;                                    // B*NC*H*16 = 4194304 f
    float* sini = sloc + (size_t)Bq*NCq*Hq*16;                     // 4194304 f
    float* pw   = sini + (size_t)Bq*NCq*Hq*16;                     // 2048 f
    float* pc2  = pw  + DEPq*Hq*Nq*2;                              // 2048 f
    float* pwL  = pc2 + DEPq*Hq*Nq*2;                              // 2048 f
    float* pwG  = pwL + DEPq*Hq*Nq*2;                              // 2048 f
    float* film = pwG + DEPq*Hq*Nq*2;                              // 2048 f
    float* ab0  = film + DEPq*Bq*2*Hq;                             // 64 f
    float* hbuf = ab0 + 64;                                        // B*L*H = 16777216 f
    float* out  = (float*)d_out;
    size_t ws_needed = (char*)(hbuf + (size_t)Bq*Lq*Hq) - (char*)d_ws;

    const int scan_grid = Bq*NCq;   // 8192 blocks (1 chunk each)

    hipLaunchKernelGGL(k_cond_film, dim3(DEPq), dim3(512), 0, stream,
                       prm,W1,b1,W2,b2,W3,b3,filmW,filmB,film);
    hipLaunchKernelGGL(k_s4params, dim3(1), dim3(DEPq*Hq*Nq), 0, stream,
                       log_dt,logAre,Aim,Cre,Cim,pw,pc2,pwL,pwG);
    hipLaunchKernelGGL(k_premix, dim3(1), dim3(Hq), 0, stream, linW, linB, eW, eb, ab0);
    hipLaunchKernelGGL(k_first, dim3(scan_grid), dim3(256), 0, stream, x, ab0, pw, sloc);
    for (int d=0; d<DEPq; d++){
        hipLaunchKernelGGL(k_pass2, dim3(Bq*Hq), dim3(256), 0, stream,
                           sloc, pwL + d*Hq*Nq*2, pwG + d*Hq*Nq*2, sini);
        if (d < DEPq-1) {
            hipLaunchKernelGGL(k_main, dim3(scan_grid), dim3(256), 0, stream,
                               x, hbuf, (d==0)?1:0, eW, eb, ab0,
                               linW + d*Hq*Hq, linB + d*Hq,
                               linW + (d+1)*Hq*Hq, linB + (d+1)*Hq,
                               pw + d*Hq*Nq*2, pc2 + d*Hq*Nq*2, pw + (d+1)*Hq*Nq*2,
                               sini, sloc,
                               Dskip + d*Hq, film + d*Bq*2*Hq, resw + d*Hq);
        } else {
            hipLaunchKernelGGL(k_last, dim3(scan_grid), dim3(256), 0, stream,
                               x, hbuf,
                               linW + d*Hq*Hq, linB + d*Hq,
                               pw + d*Hq*Nq*2, pc2 + d*Hq*Nq*2,
                               sini,
                               Dskip + d*Hq, film + d*Bq*2*Hq, resw + d*Hq,
                               cW, cb, out);
        }
    }

    static const int expected[23] = {
        Bq*Lq, Bq*2, 32, 16, 512, 32, 1024, 32, Hq, Hq,
        DEPq*Hq*Hq, DEPq*Hq, DEPq*Hq, DEPq*Hq*Nq, DEPq*Hq*Nq, DEPq*Hq*Nq, DEPq*Hq*Nq,
        DEPq*Hq, DEPq*2*Hq*32, DEPq*2*Hq, DEPq*Hq, Hq, 1
    };
    int code = 0;
    if (n_in != 23) code = 99;
    else { for (int i = 0; i < 23; i++) if (in_sizes[i] != expected[i]) { code = 100 + i; break; } }
    if (!code && ws_size < ws_needed) code = 200;
    if (code) hipLaunchKernelGGL(k_flag, dim3(1), dim3(1), 0, stream, out, code);
}